// Round 5
// baseline (118.134 us; speedup 1.0000x reference)
//
#include <hip/hip_runtime.h>
#include <math.h>

// (B,N,K,D,V,L) = (16,512,16,256,64,2)
#define Kn 16
#define Dd 256
#define NC 1024
#define MR 8192

typedef _Float16 h8 __attribute__((ext_vector_type(8)));
typedef _Float16 h4 __attribute__((ext_vector_type(4)));
typedef _Float16 h2 __attribute__((ext_vector_type(2)));
typedef float f4 __attribute__((ext_vector_type(4)));

__device__ __forceinline__ void gload16(_Float16* lds, const _Float16* g) {
  __builtin_amdgcn_global_load_lds(
      (const __attribute__((address_space(1))) void*)g,
      (__attribute__((address_space(3))) void*)lds, 16, 0, 0);
}

__device__ __forceinline__ float fsigm(float x) { return 1.f / (1.f + __expf(-x)); }
__device__ __forceinline__ float ftanh(float x) { return 2.f / (1.f + __expf(-2.f * x)) - 1.f; }

// ---------------------------------------------------------------------------
// prep kernel (one launch, independent block roles):
//   blocks [0,1024):    node_reps f32 -> h0_16 fp16 (2M elems)
//   blocks [1024,1088): P = emb @ (W+U)bottom, written直接 in W0f fragment rows
//                       k=512+vv (vv<64: in-dir, else out-dir), 2 vv per block
//   blocks [1088,1600): fold W0f top (Wi/Wo rows 0..511), Wlf (Ui/Uo top), biasq
// Fragment: Wf[kt][nt][lane][j], k = kt*32+(lane>>4)*8+j, col' = nt*16+(lane&15)
// col' = 64*(d>>4)+16*g+(d&15)  <->  c = g*256+d
// ---------------------------------------------------------------------------
__global__ __launch_bounds__(256) void prep_kernel(
    const float* __restrict__ node_reps, const float* __restrict__ emb,
    const float* __restrict__ Wi, const float* __restrict__ Wo,
    const float* __restrict__ Ui, const float* __restrict__ Uo,
    const float* __restrict__ bi, const float* __restrict__ bo,
    const float* __restrict__ bui, const float* __restrict__ buo,
    _Float16* __restrict__ h0_16, _Float16* __restrict__ W0f,
    _Float16* __restrict__ Wlf, float* __restrict__ biasq) {
  const int b = blockIdx.x, t = threadIdx.x;
  __shared__ float se[512];
  if (b < 1024) {
    const int base = b * 2048 + t * 8;
    const f4 v0 = *(const f4*)(node_reps + base);
    const f4 v1 = *(const f4*)(node_reps + base + 4);
    h8 o;
#pragma unroll
    for (int j = 0; j < 4; j++) { o[j] = (_Float16)v0[j]; o[j + 4] = (_Float16)v1[j]; }
    *(h8*)&h0_16[base] = o;
  } else if (b < 1088) {
    const int pb = b - 1024;
    const int vv0 = pb * 2;
    const int dir = vv0 >> 6;        // 0=in, 1=out
    const int v0 = vv0 & 63;
    se[t] = emb[v0 * 256 + t];
    se[256 + t] = emb[(v0 + 1) * 256 + t];
    __syncthreads();
    const int cp0 = t * 4;
    const int g = (cp0 >> 4) & 3;
    const int dd = ((cp0 >> 6) << 4) + (cp0 & 15);
    const int c = g * 256 + dd;      // cp0..cp0+3 -> c..c+3 (same g, consecutive dd)
    const float* Wa = dir ? Wo : Wi;
    const float* Ua = dir ? Uo : Ui;
    f4 a0 = {0.f, 0.f, 0.f, 0.f}, a1 = {0.f, 0.f, 0.f, 0.f};
    for (int d = 0; d < 256; d++) {
      f4 wv = *(const f4*)(Wa + (size_t)(256 + d) * NC + c);
      const f4 uv = *(const f4*)(Ua + (size_t)(256 + d) * NC + c);
      wv += uv;
      a0 += se[d] * wv;
      a1 += se[256 + d] * wv;
    }
#pragma unroll
    for (int r = 0; r < 2; r++) {
      const int vv = vv0 + r;
      const int kt = 16 + (vv >> 5), kit = vv & 31;
      const int lhi = kit >> 3, jj = kit & 7;
      const f4 av = r ? a1 : a0;
#pragma unroll
      for (int i = 0; i < 4; i++) {
        const int cp = cp0 + i;
        W0f[kt * 32768 + (cp >> 4) * 512 + (lhi * 16 + (cp & 15)) * 8 + jj] =
            (_Float16)av[i];
      }
    }
  } else {
    const int total = 512 * 1024 + 512 * 1024 + 1024;
    for (int idx = (b - 1088) * 256 + t; idx < total; idx += 512 * 256) {
      if (idx < 1024 * 1024) {
        const bool isW0 = idx < 512 * 1024;
        const int j0 = isW0 ? idx : idx - 512 * 1024;
        const int j = j0 & 7, l = (j0 >> 3) & 63, nt = (j0 >> 9) & 63, kt = j0 >> 15;
        const int k = kt * 32 + ((l >> 4) << 3) + j;
        const int cp = nt * 16 + (l & 15);
        const int g = (cp >> 4) & 3;
        const int dd = ((cp >> 6) << 4) + (cp & 15);
        const int c = g * 256 + dd;
        if (isW0) {  // W0 top 512 k-rows: [Wi_top; Wo_top]
          W0f[j0] = (_Float16)((k < 256) ? Wi[k * NC + c] : Wo[(k - 256) * NC + c]);
        } else {     // Wl: [Ui_top; Uo_top]
          Wlf[j0] = (_Float16)((k < 256) ? Ui[k * NC + c] : Uo[(k - 256) * NC + c]);
        }
      } else {
        const int cq = idx - 1024 * 1024;
        const int dd = cq >> 2, g = cq & 3;
        const int c = g * 256 + dd;
        biasq[cq] = bi[c] + bo[c] + bui[c] + buo[c];
      }
    }
  }
}

// ---------------------------------------------------------------------------
// Aggregation: one wave per row (4 rows/wave, grid-stride), no LDS/sync.
//   cmb   lane layout: [0,16)=in_idx [16,32)=in_mask [32,48)=out_idx [48,64)=out_mask
//   cmb_e lane layout: [0,16)=in_edge [16,32)=out_edge (rest duplicate)
//   lanes 0-31: in-section (cols [0,256)); lanes 32-63: out-section ([256,512))
//   16 gathers/row issued as one batch (sched_barrier-pinned), cmb prefetch.
//   BINS: bins[vv] = sum_k mask_k*[edge_k==v]; lane owns vv=2*lane(+1);
//         stored fp16 at X cols [512,640) (= k rows of P in W0f).
// ---------------------------------------------------------------------------
template <bool BINS>
__global__ __launch_bounds__(256, 4) void agg_kernel(
    const _Float16* __restrict__ hsrc,
    const int* __restrict__ iidx, const float* __restrict__ im,
    const int* __restrict__ oidx, const float* __restrict__ om,
    const int* __restrict__ ie, const int* __restrict__ oe,
    _Float16* __restrict__ X) {
  const int lane = threadIdx.x & 63;
  const int wid = threadIdx.x >> 6;
  const int xcd = blockIdx.x & 7;
  const int q = (blockIdx.x >> 3) * 4 + wid;  // 0..255 within XCD
  const int half = lane >> 5;
  const int lc = lane & 31;
  const int sel = lane >> 4, p16 = lane & 15;

  auto load_cmb = [&](int row) -> int {
    const int bb = row * Kn + p16;
    const int* a = (sel == 0)   ? (iidx + bb)
                   : (sel == 1) ? ((const int*)im + bb)
                   : (sel == 2) ? (oidx + bb)
                                : ((const int*)om + bb);
    return *a;
  };
  auto load_cmbe = [&](int row) -> int {
    return *(((lane & 16) ? oe : ie) + row * Kn + p16);
  };

  const int row0 = xcd * 1024 + q;
  int cmb = load_cmb(row0);
  int cmbe = 0;
  if (BINS) cmbe = load_cmbe(row0);

  for (int j = 0; j < 4; j++) {
    const int row = row0 + 256 * j;
    const int hb = row & ~511;
    const _Float16* hp = hsrc + ((size_t)hb << 8) + (lc << 3);

    // issue all 16 gathers
    h8 w[16];
#pragma unroll
    for (int k = 0; k < 16; k++) {
      const int ik = __shfl(cmb, (lane & 32) | k, 64);
      w[k] = *(const h8*)(hp + ((size_t)ik << 8));
    }
    // prefetch next row's index bundle
    int cmbN = 0, cmbeN = 0;
    if (j + 1 < 4) {
      cmbN = load_cmb(row + 256);
      if (BINS) cmbeN = load_cmbe(row + 256);
    }
    __builtin_amdgcn_sched_barrier(0);  // keep gather issue above the consume

    float acc[8] = {};
#pragma unroll
    for (int k = 0; k < 16; k++) {
      const float mk = __int_as_float(__shfl(cmb, (lane & 32) | 16 | k, 64));
#pragma unroll
      for (int c = 0; c < 8; c++) acc[c] += mk * (float)w[k][c];
    }

    if (BINS) {
      float b0 = 0.f, b1 = 0.f;
      const int vmine = 2 * lane - half * 64;  // 0..62 within the lane's dir
#pragma unroll
      for (int k = 0; k < 16; k++) {
        const int ei = __shfl(cmbe, k, 64);
        const int eo = __shfl(cmbe, 16 | k, 64);
        const float mi = __int_as_float(__shfl(cmb, 16 | k, 64));
        const float mo = __int_as_float(__shfl(cmb, 48 | k, 64));
        const int ec = half ? eo : ei;
        const float mc = half ? mo : mi;
        b0 += (ec == vmine) ? mc : 0.f;
        b1 += (ec == vmine + 1) ? mc : 0.f;
      }
      h2 bp;
      bp[0] = (_Float16)b0;
      bp[1] = (_Float16)b1;
      *(h2*)&X[(size_t)row * NC + 512 + lane * 2] = bp;
    }

    h8 o;
#pragma unroll
    for (int c = 0; c < 8; c++) o[c] = (_Float16)acc[c];
    *(h8*)&X[(size_t)row * NC + half * 256 + lc * 8] = o;

    cmb = cmbN;
    cmbe = cmbeN;
  }
}

// ---------------------------------------------------------------------------
// Fused MFMA GEMM + LSTM. 128x128 tile, 4 waves (2x2), 16x16x32 f16 MFMA,
// double-buffered LDS (2-phase).
//   WITH_Z: accZ over K=640 (Nh0 512 + bins 128), accL over K=512 (shared A);
//     writes zq = fp16(accZ+bias) gate-quads + LSTM0 (c=0) -> reps0, h16, cbuf.
//   !WITH_Z: accL over K=512; z = zq + accL; LSTM1 -> reps1, hbuf, cbuf.
// ---------------------------------------------------------------------------
template <bool WITH_Z, bool FIRST>
__global__ __launch_bounds__(256) void fused_gemm(
    const _Float16* __restrict__ A, const _Float16* __restrict__ W0f,
    const _Float16* __restrict__ Wlf, const float* __restrict__ biasq,
    _Float16* __restrict__ zq, const float* __restrict__ mask,
    float* __restrict__ reps, float* __restrict__ hbuf,
    _Float16* __restrict__ h16, float* __restrict__ cbuf) {
  constexpr int KT = WITH_Z ? 20 : 16;  // k-tiles of 32
  constexpr int NB = WITH_Z ? 3 : 2;
  __shared__ __align__(16) _Float16 lds[2][NB * 4096];

  const int wg = (blockIdx.x & 7) * 64 + (blockIdx.x >> 3);
  const int bm = wg >> 3, bn = wg & 7;
  const int tid = threadIdx.x, lane = tid & 63, wid = tid >> 6;
  const int wr = wid >> 1, wc = wid & 1;
  const int lr = lane & 15, lg = lane >> 4;

  f4 accL[4][4] = {};
  f4 accZ[4][4] = {};

  const _Float16* srcA0 = A + (size_t)(bm * 128 + 2 * wid * 16 + lr) * NC + lg * 8;
  const _Float16* srcBl0 = Wlf + ((size_t)bn * 8 + 2 * wid) * 512 + lane * 8;
  const _Float16* srcB00 = W0f + ((size_t)bn * 8 + 2 * wid) * 512 + lane * 8;
  const int woff = 2 * wid * 512;

  auto stage = [&](int buf, int kt) {
    _Float16* base = lds[buf];
    const _Float16* sa = srcA0 + kt * 32;
    gload16(base + woff, sa);
    gload16(base + woff + 512, sa + 16 * NC);
    if (kt < 16) {
      const _Float16* sb = srcBl0 + (size_t)kt * 32768;
      gload16(base + 4096 + woff, sb);
      gload16(base + 4096 + woff + 512, sb + 512);
    }
    if (WITH_Z) {
      const _Float16* sb = srcB00 + (size_t)kt * 32768;
      gload16(base + 8192 + woff, sb);
      gload16(base + 8192 + woff + 512, sb + 512);
    }
  };

  stage(0, 0);
  __syncthreads();
  for (int kt = 0; kt < KT; kt++) {
    const int cur = kt & 1;
    if (kt + 1 < KT) stage(cur ^ 1, kt + 1);  // prefetch under compute
    const _Float16* base = lds[cur];
    h8 a[4];
#pragma unroll
    for (int m = 0; m < 4; m++) a[m] = *(const h8*)&base[(wr * 4 + m) * 512 + lane * 8];
    if (kt < 16) {
      h8 b[4];
#pragma unroll
      for (int n = 0; n < 4; n++) b[n] = *(const h8*)&base[4096 + (wc * 4 + n) * 512 + lane * 8];
#pragma unroll
      for (int m = 0; m < 4; m++)
#pragma unroll
        for (int n = 0; n < 4; n++)
          accL[m][n] = __builtin_amdgcn_mfma_f32_16x16x32_f16(a[m], b[n], accL[m][n], 0, 0, 0);
    }
    if (WITH_Z) {
      h8 b[4];
#pragma unroll
      for (int n = 0; n < 4; n++) b[n] = *(const h8*)&base[8192 + (wc * 4 + n) * 512 + lane * 8];
#pragma unroll
      for (int m = 0; m < 4; m++)
#pragma unroll
        for (int n = 0; n < 4; n++)
          accZ[m][n] = __builtin_amdgcn_mfma_f32_16x16x32_f16(a[m], b[n], accZ[m][n], 0, 0, 0);
    }
    __syncthreads();
  }

  const int d = (bn * 2 + wc) * 16 + lr;
  const int row0 = bm * 128 + wr * 64;
  f4 bq = {0.f, 0.f, 0.f, 0.f};
  if (WITH_Z) bq = *(const f4*)&biasq[d * 4];
#pragma unroll
  for (int i = 0; i < 4; i++) {
#pragma unroll
    for (int r = 0; r < 4; r++) {
      const int row = row0 + i * 16 + lg * 4 + r;
      const size_t off = (size_t)row * Dd + d;
      float zi, zf, zo, zc;
      if (WITH_Z) {
        const float z0 = accZ[i][0][r] + bq.x;
        const float z1 = accZ[i][1][r] + bq.y;
        const float z2 = accZ[i][2][r] + bq.z;
        const float z3 = accZ[i][3][r] + bq.w;
        h4 oz;
        oz[0] = (_Float16)z0; oz[1] = (_Float16)z1;
        oz[2] = (_Float16)z2; oz[3] = (_Float16)z3;
        *(h4*)&zq[off * 4] = oz;
        zi = z0 + accL[i][0][r]; zf = z1 + accL[i][1][r];
        zo = z2 + accL[i][2][r]; zc = z3 + accL[i][3][r];
      } else {
        const h4 zb = *(const h4*)&zq[off * 4];
        zi = (float)zb[0] + accL[i][0][r]; zf = (float)zb[1] + accL[i][1][r];
        zo = (float)zb[2] + accL[i][2][r]; zc = (float)zb[3] + accL[i][3][r];
      }
      const float ig = fsigm(zi), fg = fsigm(zf), og = fsigm(zo), ci = ftanh(zc);
      const float cold = FIRST ? 0.f : cbuf[off];
      const float cn = fg * cold + ig * ci;
      const float hn = og * ftanh(cn);
      const float mk = mask[row];
      cbuf[off] = cn * mk;
      const float hm = hn * mk;
      reps[off] = hm;
      if (FIRST) h16[off] = (_Float16)hm;  // fp16 working h for iter-1 gather
      else       hbuf[off] = hm;           // final h output
    }
  }
}

// ---------------------------------------------------------------------------
extern "C" void kernel_launch(void* const* d_in, const int* in_sizes, int n_in,
                              void* d_out, int out_size, void* d_ws, size_t ws_size,
                              hipStream_t stream) {
  const float* node_reps = (const float*)d_in[0];
  const float* mask      = (const float*)d_in[1];
  const int*   in_idx    = (const int*)d_in[2];
  const int*   in_edges  = (const int*)d_in[3];
  const float* in_mask   = (const float*)d_in[4];
  const int*   out_idx   = (const int*)d_in[5];
  const int*   out_edges = (const int*)d_in[6];
  const float* out_mask  = (const float*)d_in[7];
  const float* edge_emb  = (const float*)d_in[8];
  const float* Wi  = (const float*)d_in[9];
  const float* Wo  = (const float*)d_in[10];
  const float* Ui  = (const float*)d_in[11];
  const float* Uo  = (const float*)d_in[12];
  const float* bi  = (const float*)d_in[13];
  const float* bo  = (const float*)d_in[14];
  const float* bui = (const float*)d_in[15];
  const float* buo = (const float*)d_in[16];

  float* out = (float*)d_out;
  const size_t MD = (size_t)MR * Dd;
  float* reps0 = out;
  float* reps1 = out + MD;
  float* hbuf  = out + 2 * MD;
  float* cbuf  = out + 3 * MD;

  _Float16* X    = (_Float16*)d_ws;                 // 8192*1024 (16 MB)
  _Float16* zq   = X + (size_t)MR * NC;             // 16 MB
  _Float16* W0f  = zq + (size_t)MR * NC;            // 640*1024 (1.25 MB)
  _Float16* Wlf  = W0f + 640 * 1024;                // 512*1024 (1 MB)
  _Float16* h0   = Wlf + 512 * 1024;                // 4 MB
  _Float16* h16  = h0 + (size_t)MR * Dd;            // 4 MB
  float*    biasq = (float*)(h16 + (size_t)MR * Dd);

  // 1. node cvt fp16 || P = emb @ (W+U)bot || weight fold/permute || bias
  prep_kernel<<<1600, 256, 0, stream>>>(node_reps, edge_emb, Wi, Wo, Ui, Uo,
                                        bi, bo, bui, buo, h0, W0f, Wlf, biasq);
  // 2. aggregate h0 -> X[:, :512) Nh + X[:, 512:640) edge bins
  agg_kernel<true><<<512, 256, 0, stream>>>(h0, in_idx, in_mask, out_idx,
                                            out_mask, in_edges, out_edges, X);
  // 3. dual-acc GEMM: zbase (K=640) + iter-0 loop GEMM (K=512) + LSTM0
  fused_gemm<true, true><<<512, 256, 0, stream>>>(
      X, W0f, Wlf, biasq, zq, mask, reps0, nullptr, h16, cbuf);
  // 4. re-aggregate from fp16 h1
  agg_kernel<false><<<512, 256, 0, stream>>>(h16, in_idx, in_mask, out_idx,
                                             out_mask, nullptr, nullptr, X);
  // 5. iter-1 GEMM (K=512) + LSTM1 -> final outputs
  fused_gemm<false, false><<<512, 256, 0, stream>>>(
      X, W0f, Wlf, biasq, zq, mask, reps1, hbuf, h16, cbuf);
}

// Round 6
// 93.012 us; speedup vs baseline: 1.2701x; 1.2701x over previous
//
#include <hip/hip_runtime.h>
#include <math.h>

// (B,N,K,D,V,L) = (16,512,16,256,64,2)
#define Kn 16
#define Dd 256
#define NC 1024
#define MR 8192

typedef _Float16 h8 __attribute__((ext_vector_type(8)));
typedef _Float16 h4 __attribute__((ext_vector_type(4)));
typedef _Float16 h2 __attribute__((ext_vector_type(2)));
typedef float f4 __attribute__((ext_vector_type(4)));

__device__ __forceinline__ void gload16(_Float16* lds, const _Float16* g) {
  __builtin_amdgcn_global_load_lds(
      (const __attribute__((address_space(1))) void*)g,
      (__attribute__((address_space(3))) void*)lds, 16, 0, 0);
}

__device__ __forceinline__ float fsigm(float x) { return 1.f / (1.f + __expf(-x)); }
__device__ __forceinline__ float ftanh(float x) { return 2.f / (1.f + __expf(-2.f * x)) - 1.f; }

// ---------------------------------------------------------------------------
// prep kernel, role-split grid (417 blocks):
//   [0,256):   P = emb @ (W+U)bottom  -> W0f fragment rows k=512+vv
//              block = (vv-pair, col-quarter); K-split over 4 waves; LDS reduce
//   [256,288): fold W0top (Wi/Wo rows) / Wl (Ui/Uo top) -> fragment planes
//              coalesced reads, LDS plane in final fragment layout, linear copy out
//   [288,416): node_reps f32 -> h0 fp16
//   416:       biasq
// Fragment: Wf[kt][nt][lane][j], k = kt*32+(lane>>4)*8+j, cp = nt*16+(lane&15)
// col perm:  cp = 64*(d>>4)+16*g+(d&15)  <->  c = g*256+d
// ---------------------------------------------------------------------------
__global__ __launch_bounds__(256) void prep_kernel(
    const float* __restrict__ node_reps, const float* __restrict__ emb,
    const float* __restrict__ Wi, const float* __restrict__ Wo,
    const float* __restrict__ Ui, const float* __restrict__ Uo,
    const float* __restrict__ bi, const float* __restrict__ bo,
    const float* __restrict__ bui, const float* __restrict__ buo,
    _Float16* __restrict__ h0_16, _Float16* __restrict__ W0f,
    _Float16* __restrict__ Wlf, float* __restrict__ biasq) {
  __shared__ __align__(16) char smem[65536];
  const int b = blockIdx.x, t = threadIdx.x;

  if (b < 256) {
    // ---- role P ----
    float* se = (float*)smem;            // [512] two emb rows
    float* sa = (float*)(smem + 2048);   // [2][4][64][4] partials (8 KB)
    const int vvp = b >> 2, cq = b & 3;
    const int dir = vvp >> 5;
    const int v0 = (vvp * 2) & 63;
    const float* Wa = dir ? Wo : Wi;
    const float* Ua = dir ? Uo : Ui;
    se[t] = emb[v0 * 256 + t];
    se[256 + t] = emb[v0 * 256 + 256 + t];
    __syncthreads();
    const int l = t & 63, ds = t >> 6;
    const int cp0 = cq * 256 + l * 4;
    const int g = (cp0 >> 4) & 3;
    const int d0 = ((cp0 >> 6) << 4) + (cp0 & 15);
    const int c0 = g * 256 + d0;
    f4 a0 = {0.f, 0.f, 0.f, 0.f}, a1 = {0.f, 0.f, 0.f, 0.f};
    const float* wp = Wa + (size_t)(256 + ds * 64) * NC + c0;
    const float* up = Ua + (size_t)(256 + ds * 64) * NC + c0;
    for (int dd = 0; dd < 64; dd++) {
      const f4 wv = *(const f4*)(wp + (size_t)dd * NC) + *(const f4*)(up + (size_t)dd * NC);
      a0 += se[ds * 64 + dd] * wv;
      a1 += se[256 + ds * 64 + dd] * wv;
    }
    *(f4*)&sa[((0 * 4 + ds) * 64 + l) * 4] = a0;
    *(f4*)&sa[((1 * 4 + ds) * 64 + l) * 4] = a1;
    __syncthreads();
    if (t < 128) {
      const int vs = t >> 6, fc = t & 63;
      f4 s = {0.f, 0.f, 0.f, 0.f};
#pragma unroll
      for (int d = 0; d < 4; d++) s += *(const f4*)&sa[((vs * 4 + d) * 64 + fc) * 4];
      const int vvg = vvp * 2 + vs;
      const int kt = 16 + (vvg >> 5);
      const int lhi = (vvg >> 3) & 3;
      const int j = vvg & 7;
      const int cpb = cq * 256 + fc * 4;
#pragma unroll
      for (int i = 0; i < 4; i++) {
        const int cp = cpb + i;
        W0f[kt * 32768 + (cp >> 4) * 512 + (lhi * 16 + (cp & 15)) * 8 + j] = (_Float16)s[i];
      }
    }
  } else if (b < 288) {
    // ---- role fold ----
    _Float16* S = (_Float16*)smem;  // fragment-layout plane [32768]
    const int p = b - 256;          // 0..15 -> W0f kt=p ; 16..31 -> Wlf kt=p-16
    const int l = t & 63;
    const int j0 = ((t >> 6) & 1) * 4;
    const int kk = (p & 15) * 32 + ((l >> 4) << 3) + j0;  // source row base (4 rows)
    const float* rowp = (p < 16)
        ? (kk < 256 ? Wi + (size_t)kk * NC : Wo + (size_t)(kk - 256) * NC)
        : (kk < 256 ? Ui + (size_t)kk * NC : Uo + (size_t)(kk - 256) * NC);
#pragma unroll 4
    for (int it = 0; it < 32; it++) {
      const int nt = it * 2 + (t >> 7);
      const int cp = nt * 16 + (l & 15);
      const int g = (cp >> 4) & 3;
      const int d = ((cp >> 6) << 4) + (cp & 15);
      const int c = g * 256 + d;
      h4 w;
      w[0] = (_Float16)rowp[c];
      w[1] = (_Float16)rowp[NC + c];
      w[2] = (_Float16)rowp[2 * NC + c];
      w[3] = (_Float16)rowp[3 * NC + c];
      *(h4*)&S[nt * 512 + l * 8 + j0] = w;
    }
    __syncthreads();
    _Float16* dst = (p < 16) ? (W0f + p * 32768) : (Wlf + (p - 16) * 32768);
#pragma unroll
    for (int it = 0; it < 16; it++) {
      const int off = it * 2048 + t * 8;
      *(h8*)&dst[off] = *(const h8*)&S[off];
    }
  } else if (b < 416) {
    // ---- role cvt: node_reps -> fp16 ----
    const int cb = b - 288;
#pragma unroll
    for (int r = 0; r < 8; r++) {
      const int off = cb * 16384 + r * 2048 + t * 8;
      const f4 v0 = *(const f4*)(node_reps + off);
      const f4 v1 = *(const f4*)(node_reps + off + 4);
      h8 o;
#pragma unroll
      for (int jj = 0; jj < 4; jj++) { o[jj] = (_Float16)v0[jj]; o[jj + 4] = (_Float16)v1[jj]; }
      *(h8*)&h0_16[off] = o;
    }
  } else {
    // ---- role bias ----
#pragma unroll
    for (int i = 0; i < 4; i++) {
      const int cq = t * 4 + i;
      const int dd = cq >> 2, g = cq & 3;
      const int c = g * 256 + dd;
      biasq[cq] = bi[c] + bo[c] + bui[c] + buo[c];
    }
  }
}

// ---------------------------------------------------------------------------
// Aggregation: one wave per row (4 rows/wave), no LDS/sync. (unchanged R5)
// ---------------------------------------------------------------------------
template <bool BINS>
__global__ __launch_bounds__(256, 4) void agg_kernel(
    const _Float16* __restrict__ hsrc,
    const int* __restrict__ iidx, const float* __restrict__ im,
    const int* __restrict__ oidx, const float* __restrict__ om,
    const int* __restrict__ ie, const int* __restrict__ oe,
    _Float16* __restrict__ X) {
  const int lane = threadIdx.x & 63;
  const int wid = threadIdx.x >> 6;
  const int xcd = blockIdx.x & 7;
  const int q = (blockIdx.x >> 3) * 4 + wid;
  const int half = lane >> 5;
  const int lc = lane & 31;
  const int sel = lane >> 4, p16 = lane & 15;

  auto load_cmb = [&](int row) -> int {
    const int bb = row * Kn + p16;
    const int* a = (sel == 0)   ? (iidx + bb)
                   : (sel == 1) ? ((const int*)im + bb)
                   : (sel == 2) ? (oidx + bb)
                                : ((const int*)om + bb);
    return *a;
  };
  auto load_cmbe = [&](int row) -> int {
    return *(((lane & 16) ? oe : ie) + row * Kn + p16);
  };

  const int row0 = xcd * 1024 + q;
  int cmb = load_cmb(row0);
  int cmbe = 0;
  if (BINS) cmbe = load_cmbe(row0);

  for (int j = 0; j < 4; j++) {
    const int row = row0 + 256 * j;
    const int hb = row & ~511;
    const _Float16* hp = hsrc + ((size_t)hb << 8) + (lc << 3);

    h8 w[16];
#pragma unroll
    for (int k = 0; k < 16; k++) {
      const int ik = __shfl(cmb, (lane & 32) | k, 64);
      w[k] = *(const h8*)(hp + ((size_t)ik << 8));
    }
    int cmbN = 0, cmbeN = 0;
    if (j + 1 < 4) {
      cmbN = load_cmb(row + 256);
      if (BINS) cmbeN = load_cmbe(row + 256);
    }
    __builtin_amdgcn_sched_barrier(0);

    float acc[8] = {};
#pragma unroll
    for (int k = 0; k < 16; k++) {
      const float mk = __int_as_float(__shfl(cmb, (lane & 32) | 16 | k, 64));
#pragma unroll
      for (int c = 0; c < 8; c++) acc[c] += mk * (float)w[k][c];
    }

    if (BINS) {
      float b0 = 0.f, b1 = 0.f;
      const int vmine = 2 * lane - half * 64;
#pragma unroll
      for (int k = 0; k < 16; k++) {
        const int ei = __shfl(cmbe, k, 64);
        const int eo = __shfl(cmbe, 16 | k, 64);
        const float mi = __int_as_float(__shfl(cmb, 16 | k, 64));
        const float mo = __int_as_float(__shfl(cmb, 48 | k, 64));
        const int ec = half ? eo : ei;
        const float mc = half ? mo : mi;
        b0 += (ec == vmine) ? mc : 0.f;
        b1 += (ec == vmine + 1) ? mc : 0.f;
      }
      h2 bp;
      bp[0] = (_Float16)b0;
      bp[1] = (_Float16)b1;
      *(h2*)&X[(size_t)row * NC + 512 + lane * 2] = bp;
    }

    h8 o;
#pragma unroll
    for (int c = 0; c < 8; c++) o[c] = (_Float16)acc[c];
    *(h8*)&X[(size_t)row * NC + half * 256 + lc * 8] = o;

    cmb = cmbN;
    cmbe = cmbeN;
  }
}

// ---------------------------------------------------------------------------
// Fused MFMA GEMM + LSTM (unchanged R5). 128x128 tile, 4 waves, dbuf LDS.
// ---------------------------------------------------------------------------
template <bool WITH_Z, bool FIRST>
__global__ __launch_bounds__(256) void fused_gemm(
    const _Float16* __restrict__ A, const _Float16* __restrict__ W0f,
    const _Float16* __restrict__ Wlf, const float* __restrict__ biasq,
    _Float16* __restrict__ zq, const float* __restrict__ mask,
    float* __restrict__ reps, float* __restrict__ hbuf,
    _Float16* __restrict__ h16, float* __restrict__ cbuf) {
  constexpr int KT = WITH_Z ? 20 : 16;
  constexpr int NB = WITH_Z ? 3 : 2;
  __shared__ __align__(16) _Float16 lds[2][NB * 4096];

  const int wg = (blockIdx.x & 7) * 64 + (blockIdx.x >> 3);
  const int bm = wg >> 3, bn = wg & 7;
  const int tid = threadIdx.x, lane = tid & 63, wid = tid >> 6;
  const int wr = wid >> 1, wc = wid & 1;
  const int lr = lane & 15, lg = lane >> 4;

  f4 accL[4][4] = {};
  f4 accZ[4][4] = {};

  const _Float16* srcA0 = A + (size_t)(bm * 128 + 2 * wid * 16 + lr) * NC + lg * 8;
  const _Float16* srcBl0 = Wlf + ((size_t)bn * 8 + 2 * wid) * 512 + lane * 8;
  const _Float16* srcB00 = W0f + ((size_t)bn * 8 + 2 * wid) * 512 + lane * 8;
  const int woff = 2 * wid * 512;

  auto stage = [&](int buf, int kt) {
    _Float16* base = lds[buf];
    const _Float16* sa = srcA0 + kt * 32;
    gload16(base + woff, sa);
    gload16(base + woff + 512, sa + 16 * NC);
    if (kt < 16) {
      const _Float16* sb = srcBl0 + (size_t)kt * 32768;
      gload16(base + 4096 + woff, sb);
      gload16(base + 4096 + woff + 512, sb + 512);
    }
    if (WITH_Z) {
      const _Float16* sb = srcB00 + (size_t)kt * 32768;
      gload16(base + 8192 + woff, sb);
      gload16(base + 8192 + woff + 512, sb + 512);
    }
  };

  stage(0, 0);
  __syncthreads();
  for (int kt = 0; kt < KT; kt++) {
    const int cur = kt & 1;
    if (kt + 1 < KT) stage(cur ^ 1, kt + 1);
    const _Float16* base = lds[cur];
    h8 a[4];
#pragma unroll
    for (int m = 0; m < 4; m++) a[m] = *(const h8*)&base[(wr * 4 + m) * 512 + lane * 8];
    if (kt < 16) {
      h8 b[4];
#pragma unroll
      for (int n = 0; n < 4; n++) b[n] = *(const h8*)&base[4096 + (wc * 4 + n) * 512 + lane * 8];
#pragma unroll
      for (int m = 0; m < 4; m++)
#pragma unroll
        for (int n = 0; n < 4; n++)
          accL[m][n] = __builtin_amdgcn_mfma_f32_16x16x32_f16(a[m], b[n], accL[m][n], 0, 0, 0);
    }
    if (WITH_Z) {
      h8 b[4];
#pragma unroll
      for (int n = 0; n < 4; n++) b[n] = *(const h8*)&base[8192 + (wc * 4 + n) * 512 + lane * 8];
#pragma unroll
      for (int m = 0; m < 4; m++)
#pragma unroll
        for (int n = 0; n < 4; n++)
          accZ[m][n] = __builtin_amdgcn_mfma_f32_16x16x32_f16(a[m], b[n], accZ[m][n], 0, 0, 0);
    }
    __syncthreads();
  }

  const int d = (bn * 2 + wc) * 16 + lr;
  const int row0 = bm * 128 + wr * 64;
  f4 bq = {0.f, 0.f, 0.f, 0.f};
  if (WITH_Z) bq = *(const f4*)&biasq[d * 4];
#pragma unroll
  for (int i = 0; i < 4; i++) {
#pragma unroll
    for (int r = 0; r < 4; r++) {
      const int row = row0 + i * 16 + lg * 4 + r;
      const size_t off = (size_t)row * Dd + d;
      float zi, zf, zo, zc;
      if (WITH_Z) {
        const float z0 = accZ[i][0][r] + bq.x;
        const float z1 = accZ[i][1][r] + bq.y;
        const float z2 = accZ[i][2][r] + bq.z;
        const float z3 = accZ[i][3][r] + bq.w;
        h4 oz;
        oz[0] = (_Float16)z0; oz[1] = (_Float16)z1;
        oz[2] = (_Float16)z2; oz[3] = (_Float16)z3;
        *(h4*)&zq[off * 4] = oz;
        zi = z0 + accL[i][0][r]; zf = z1 + accL[i][1][r];
        zo = z2 + accL[i][2][r]; zc = z3 + accL[i][3][r];
      } else {
        const h4 zb = *(const h4*)&zq[off * 4];
        zi = (float)zb[0] + accL[i][0][r]; zf = (float)zb[1] + accL[i][1][r];
        zo = (float)zb[2] + accL[i][2][r]; zc = (float)zb[3] + accL[i][3][r];
      }
      const float ig = fsigm(zi), fg = fsigm(zf), og = fsigm(zo), ci = ftanh(zc);
      const float cold = FIRST ? 0.f : cbuf[off];
      const float cn = fg * cold + ig * ci;
      const float hn = og * ftanh(cn);
      const float mk = mask[row];
      cbuf[off] = cn * mk;
      const float hm = hn * mk;
      reps[off] = hm;
      if (FIRST) h16[off] = (_Float16)hm;
      else       hbuf[off] = hm;
    }
  }
}

// ---------------------------------------------------------------------------
extern "C" void kernel_launch(void* const* d_in, const int* in_sizes, int n_in,
                              void* d_out, int out_size, void* d_ws, size_t ws_size,
                              hipStream_t stream) {
  const float* node_reps = (const float*)d_in[0];
  const float* mask      = (const float*)d_in[1];
  const int*   in_idx    = (const int*)d_in[2];
  const int*   in_edges  = (const int*)d_in[3];
  const float* in_mask   = (const float*)d_in[4];
  const int*   out_idx   = (const int*)d_in[5];
  const int*   out_edges = (const int*)d_in[6];
  const float* out_mask  = (const float*)d_in[7];
  const float* edge_emb  = (const float*)d_in[8];
  const float* Wi  = (const float*)d_in[9];
  const float* Wo  = (const float*)d_in[10];
  const float* Ui  = (const float*)d_in[11];
  const float* Uo  = (const float*)d_in[12];
  const float* bi  = (const float*)d_in[13];
  const float* bo  = (const float*)d_in[14];
  const float* bui = (const float*)d_in[15];
  const float* buo = (const float*)d_in[16];

  float* out = (float*)d_out;
  const size_t MD = (size_t)MR * Dd;
  float* reps0 = out;
  float* reps1 = out + MD;
  float* hbuf  = out + 2 * MD;
  float* cbuf  = out + 3 * MD;

  _Float16* X    = (_Float16*)d_ws;                 // 16 MB
  _Float16* zq   = X + (size_t)MR * NC;             // 16 MB
  _Float16* W0f  = zq + (size_t)MR * NC;            // 640*1024 (1.25 MB)
  _Float16* Wlf  = W0f + 640 * 1024;                // 512*1024 (1 MB)
  _Float16* h0   = Wlf + 512 * 1024;                // 4 MB
  _Float16* h16  = h0 + (size_t)MR * Dd;            // 4 MB
  float*    biasq = (float*)(h16 + (size_t)MR * Dd);

  // 1. P-GEMM || fold || node cvt || bias (role-split, balanced)
  prep_kernel<<<417, 256, 0, stream>>>(node_reps, edge_emb, Wi, Wo, Ui, Uo,
                                       bi, bo, bui, buo, h0, W0f, Wlf, biasq);
  // 2. aggregate h0 -> X[:, :512) Nh + X[:, 512:640) edge bins
  agg_kernel<true><<<512, 256, 0, stream>>>(h0, in_idx, in_mask, out_idx,
                                            out_mask, in_edges, out_edges, X);
  // 3. dual-acc GEMM: zbase (K=640) + iter-0 loop GEMM (K=512) + LSTM0
  fused_gemm<true, true><<<512, 256, 0, stream>>>(
      X, W0f, Wlf, biasq, zq, mask, reps0, nullptr, h16, cbuf);
  // 4. re-aggregate from fp16 h1
  agg_kernel<false><<<512, 256, 0, stream>>>(h16, in_idx, in_mask, out_idx,
                                             out_mask, nullptr, nullptr, X);
  // 5. iter-1 GEMM (K=512) + LSTM1 -> final outputs
  fused_gemm<false, false><<<512, 256, 0, stream>>>(
      X, W0f, Wlf, biasq, zq, mask, reps1, hbuf, h16, cbuf);
}

// Round 7
// 91.171 us; speedup vs baseline: 1.2957x; 1.0202x over previous
//
#include <hip/hip_runtime.h>
#include <math.h>

// (B,N,K,D,V,L) = (16,512,16,256,64,2)
#define Kn 16
#define Dd 256
#define NC 1024
#define MR 8192

typedef _Float16 h8 __attribute__((ext_vector_type(8)));
typedef _Float16 h4 __attribute__((ext_vector_type(4)));
typedef _Float16 h2 __attribute__((ext_vector_type(2)));
typedef float f4 __attribute__((ext_vector_type(4)));

__device__ __forceinline__ void gload16(_Float16* lds, const _Float16* g) {
  __builtin_amdgcn_global_load_lds(
      (const __attribute__((address_space(1))) void*)g,
      (__attribute__((address_space(3))) void*)lds, 16, 0, 0);
}

__device__ __forceinline__ float fsigm(float x) { return 1.f / (1.f + __expf(-x)); }
__device__ __forceinline__ float ftanh(float x) { return 2.f / (1.f + __expf(-2.f * x)) - 1.f; }

// ---------------------------------------------------------------------------
// mega kernel, role-split grid (801 blocks):
//   [0,256):   P = emb @ (W+U)bottom -> W0f fragment rows k=512+vv
//   [256,288): fold W0top (Wi/Wo) / Wl (Ui/Uo top) -> fragments, direct stores
//   288:       biasq
//   [289,801): agg0: wave-per-row gather from f32 node_reps + edge bins -> X
// Fragment: Wf[kt][nt][lane][j], k = kt*32+(lane>>4)*8+j, cp = nt*16+(lane&15)
// col perm:  cp = 64*(d>>4)+16*g+(d&15)  <->  c = g*256+d
// ---------------------------------------------------------------------------
__global__ __launch_bounds__(256) void mega_kernel(
    const float* __restrict__ node_reps, const float* __restrict__ emb,
    const int* __restrict__ iidx, const float* __restrict__ im,
    const int* __restrict__ oidx, const float* __restrict__ om,
    const int* __restrict__ ie, const int* __restrict__ oe,
    const float* __restrict__ Wi, const float* __restrict__ Wo,
    const float* __restrict__ Ui, const float* __restrict__ Uo,
    const float* __restrict__ bi, const float* __restrict__ bo,
    const float* __restrict__ bui, const float* __restrict__ buo,
    _Float16* __restrict__ X, _Float16* __restrict__ W0f,
    _Float16* __restrict__ Wlf, float* __restrict__ biasq) {
  __shared__ __align__(16) char smem[10240];
  const int b = blockIdx.x, t = threadIdx.x;

  if (b < 256) {
    // ---- role P ----
    float* se = (float*)smem;            // [512] two emb rows
    float* sa = (float*)(smem + 2048);   // [2][4][64][4] partials (8 KB)
    const int vvp = b >> 2, cq = b & 3;
    const int dir = vvp >> 5;
    const int v0 = (vvp * 2) & 63;
    const float* Wa = dir ? Wo : Wi;
    const float* Ua = dir ? Uo : Ui;
    se[t] = emb[v0 * 256 + t];
    se[256 + t] = emb[v0 * 256 + 256 + t];
    __syncthreads();
    const int l = t & 63, ds = t >> 6;
    const int cp0 = cq * 256 + l * 4;
    const int g = (cp0 >> 4) & 3;
    const int d0 = ((cp0 >> 6) << 4) + (cp0 & 15);
    const int c0 = g * 256 + d0;
    f4 a0 = {0.f, 0.f, 0.f, 0.f}, a1 = {0.f, 0.f, 0.f, 0.f};
    const float* wp = Wa + (size_t)(256 + ds * 64) * NC + c0;
    const float* up = Ua + (size_t)(256 + ds * 64) * NC + c0;
    for (int dd = 0; dd < 64; dd++) {
      const f4 wv = *(const f4*)(wp + (size_t)dd * NC) + *(const f4*)(up + (size_t)dd * NC);
      a0 += se[ds * 64 + dd] * wv;
      a1 += se[256 + ds * 64 + dd] * wv;
    }
    *(f4*)&sa[((0 * 4 + ds) * 64 + l) * 4] = a0;
    *(f4*)&sa[((1 * 4 + ds) * 64 + l) * 4] = a1;
    __syncthreads();
    if (t < 128) {
      const int vs = t >> 6, fc = t & 63;
      f4 s = {0.f, 0.f, 0.f, 0.f};
#pragma unroll
      for (int d = 0; d < 4; d++) s += *(const f4*)&sa[((vs * 4 + d) * 64 + fc) * 4];
      const int vvg = vvp * 2 + vs;
      const int kt = 16 + (vvg >> 5);
      const int lhi = (vvg >> 3) & 3;
      const int j = vvg & 7;
      const int cpb = cq * 256 + fc * 4;
#pragma unroll
      for (int i = 0; i < 4; i++) {
        const int cp = cpb + i;
        W0f[kt * 32768 + (cp >> 4) * 512 + (lhi * 16 + (cp & 15)) * 8 + j] = (_Float16)s[i];
      }
    }
  } else if (b < 288) {
    // ---- role fold: direct fragment stores (no LDS) ----
    const int p = b - 256;          // 0..15 -> W0f kt=p ; 16..31 -> Wlf kt=p-16
    const int l = t & 63;
    const int j0 = ((t >> 6) & 1) * 4;
    const int kk = (p & 15) * 32 + ((l >> 4) << 3) + j0;  // source row base (4 rows)
    const float* rowp = (p < 16)
        ? (kk < 256 ? Wi + (size_t)kk * NC : Wo + (size_t)(kk - 256) * NC)
        : (kk < 256 ? Ui + (size_t)kk * NC : Uo + (size_t)(kk - 256) * NC);
    _Float16* dst = (p < 16) ? (W0f + p * 32768) : (Wlf + (p - 16) * 32768);
#pragma unroll 4
    for (int it = 0; it < 32; it++) {
      const int nt = it * 2 + (t >> 7);
      const int cp = nt * 16 + (l & 15);
      const int g = (cp >> 4) & 3;
      const int d = ((cp >> 6) << 4) + (cp & 15);
      const int c = g * 256 + d;
      h4 w;
      w[0] = (_Float16)rowp[c];
      w[1] = (_Float16)rowp[NC + c];
      w[2] = (_Float16)rowp[2 * NC + c];
      w[3] = (_Float16)rowp[3 * NC + c];
      *(h4*)&dst[nt * 512 + l * 8 + j0] = w;
    }
  } else if (b == 288) {
    // ---- role bias ----
#pragma unroll
    for (int i = 0; i < 4; i++) {
      const int cq = t * 4 + i;
      const int dd = cq >> 2, g = cq & 3;
      const int c = g * 256 + dd;
      biasq[cq] = bi[c] + bo[c] + bui[c] + buo[c];
    }
  } else {
    // ---- role agg0: wave-per-row, f32 gathers from node_reps, bins ----
    const int ab = b - 289;
    const int lane = t & 63;
    const int wid = t >> 6;
    const int xcd = ab & 7;
    const int q = (ab >> 3) * 4 + wid;
    const int half = lane >> 5;
    const int lc = lane & 31;
    const int sel = lane >> 4, p16 = lane & 15;

    auto load_cmb = [&](int row) -> int {
      const int bb = row * Kn + p16;
      const int* a = (sel == 0)   ? (iidx + bb)
                     : (sel == 1) ? ((const int*)im + bb)
                     : (sel == 2) ? (oidx + bb)
                                  : ((const int*)om + bb);
      return *a;
    };
    auto load_cmbe = [&](int row) -> int {
      return *(((lane & 16) ? oe : ie) + row * Kn + p16);
    };

    const int row0 = xcd * 1024 + q;
    int cmb = load_cmb(row0);
    int cmbe = load_cmbe(row0);

    for (int j = 0; j < 4; j++) {
      const int row = row0 + 256 * j;
      const int hb = row & ~511;
      const float* hp = node_reps + ((size_t)hb << 8) + (lc << 3);

      float acc[8] = {};
      int cmbN = 0, cmbeN = 0;
#pragma unroll
      for (int kb = 0; kb < 2; kb++) {
        f4 w0[8], w1[8];
#pragma unroll
        for (int k = 0; k < 8; k++) {
          const int ik = __shfl(cmb, (lane & 32) | (kb * 8 + k), 64);
          const float* p = hp + ((size_t)ik << 8);
          w0[k] = *(const f4*)p;
          w1[k] = *(const f4*)(p + 4);
        }
        if (kb == 0 && j + 1 < 4) {  // prefetch next row's bundles under the gathers
          cmbN = load_cmb(row + 256);
          cmbeN = load_cmbe(row + 256);
        }
        __builtin_amdgcn_sched_barrier(0);
#pragma unroll
        for (int k = 0; k < 8; k++) {
          const float mk = __int_as_float(__shfl(cmb, (lane & 32) | 16 | (kb * 8 + k), 64));
#pragma unroll
          for (int c = 0; c < 4; c++) {
            acc[c] += mk * w0[k][c];
            acc[4 + c] += mk * w1[k][c];
          }
        }
      }

      {  // edge bins
        float b0 = 0.f, b1 = 0.f;
        const int vmine = 2 * lane - half * 64;
#pragma unroll
        for (int k = 0; k < 16; k++) {
          const int ec = __shfl(cmbe, (half << 4) | k, 64);
          const float mc = __int_as_float(__shfl(cmb, (lane & 32) | 16 | k, 64));
          b0 += (ec == vmine) ? mc : 0.f;
          b1 += (ec == vmine + 1) ? mc : 0.f;
        }
        h2 bp;
        bp[0] = (_Float16)b0;
        bp[1] = (_Float16)b1;
        *(h2*)&X[(size_t)row * NC + 512 + lane * 2] = bp;
      }

      h8 o;
#pragma unroll
      for (int c = 0; c < 8; c++) o[c] = (_Float16)acc[c];
      *(h8*)&X[(size_t)row * NC + half * 256 + lc * 8] = o;

      cmb = cmbN;
      cmbe = cmbeN;
    }
  }
}

// ---------------------------------------------------------------------------
// Iter-1 aggregation from fp16 h copy -> X cols [0,512). (R5 structure)
// ---------------------------------------------------------------------------
__global__ __launch_bounds__(256, 4) void agg1_kernel(
    const _Float16* __restrict__ h16,
    const int* __restrict__ iidx, const float* __restrict__ im,
    const int* __restrict__ oidx, const float* __restrict__ om,
    _Float16* __restrict__ X) {
  const int lane = threadIdx.x & 63;
  const int wid = threadIdx.x >> 6;
  const int xcd = blockIdx.x & 7;
  const int q = (blockIdx.x >> 3) * 4 + wid;
  const int half = lane >> 5;
  const int lc = lane & 31;
  const int sel = lane >> 4, p16 = lane & 15;

  auto load_cmb = [&](int row) -> int {
    const int bb = row * Kn + p16;
    const int* a = (sel == 0)   ? (iidx + bb)
                   : (sel == 1) ? ((const int*)im + bb)
                   : (sel == 2) ? (oidx + bb)
                                : ((const int*)om + bb);
    return *a;
  };

  const int row0 = xcd * 1024 + q;
  int cmb = load_cmb(row0);

  for (int j = 0; j < 4; j++) {
    const int row = row0 + 256 * j;
    const int hb = row & ~511;
    const _Float16* hp = h16 + ((size_t)hb << 8) + (lc << 3);

    h8 w[16];
#pragma unroll
    for (int k = 0; k < 16; k++) {
      const int ik = __shfl(cmb, (lane & 32) | k, 64);
      w[k] = *(const h8*)(hp + ((size_t)ik << 8));
    }
    int cmbN = 0;
    if (j + 1 < 4) cmbN = load_cmb(row + 256);
    __builtin_amdgcn_sched_barrier(0);

    float acc[8] = {};
#pragma unroll
    for (int k = 0; k < 16; k++) {
      const float mk = __int_as_float(__shfl(cmb, (lane & 32) | 16 | k, 64));
#pragma unroll
      for (int c = 0; c < 8; c++) acc[c] += mk * (float)w[k][c];
    }

    h8 o;
#pragma unroll
    for (int c = 0; c < 8; c++) o[c] = (_Float16)acc[c];
    *(h8*)&X[(size_t)row * NC + half * 256 + lc * 8] = o;

    cmb = cmbN;
  }
}

// ---------------------------------------------------------------------------
// Fused MFMA GEMM + LSTM. 128x128 tile, 4 waves (2x2), 16x16x32 f16 MFMA.
// 3-buffer pipeline, ONE raw barrier per K-step, counted vmcnt (never 0 in
// steady state), setprio(1) around the MFMA cluster.
//   iter kt: [stage kt+2] [ds_read buf kt; lgkmcnt0; sched_barrier]
//            [MFMA] [vmcnt(D); barrier]   -- vmcnt(D) => stage kt+1 retired.
// ---------------------------------------------------------------------------
template <bool WITH_Z, bool FIRST>
__global__ __launch_bounds__(256) void fused_gemm(
    const _Float16* __restrict__ A, const _Float16* __restrict__ W0f,
    const _Float16* __restrict__ Wlf, const float* __restrict__ biasq,
    _Float16* __restrict__ zq, const float* __restrict__ mask,
    float* __restrict__ reps, float* __restrict__ hbuf,
    _Float16* __restrict__ h16, float* __restrict__ cbuf) {
  constexpr int KT = WITH_Z ? 20 : 16;
  constexpr int NB = WITH_Z ? 3 : 2;     // planes per buffer
  constexpr int D = WITH_Z ? 6 : 4;      // gload_lds per stage per wave
  __shared__ __align__(16) _Float16 lds[3][NB * 4096];

  const int wg = (blockIdx.x & 7) * 64 + (blockIdx.x >> 3);
  const int bm = wg >> 3, bn = wg & 7;
  const int tid = threadIdx.x, lane = tid & 63, wid = tid >> 6;
  const int wr = wid >> 1, wc = wid & 1;
  const int lr = lane & 15, lg = lane >> 4;

  f4 accL[4][4] = {};
  f4 accZ[4][4] = {};

  const _Float16* srcA0 = A + (size_t)(bm * 128 + 2 * wid * 16 + lr) * NC + lg * 8;
  const _Float16* srcBl0 = Wlf + ((size_t)bn * 8 + 2 * wid) * 512 + lane * 8;
  const _Float16* srcB00 = W0f + ((size_t)bn * 8 + 2 * wid) * 512 + lane * 8;
  const int woff = 2 * wid * 512;

  auto stage = [&](int buf, int kt) {
    _Float16* base = lds[buf];
    const _Float16* sa = srcA0 + kt * 32;
    gload16(base + woff, sa);
    gload16(base + woff + 512, sa + 16 * NC);
    // uniform load count: clamp Bl tile index (dummy re-load for kt>=16)
    const _Float16* sbl = srcBl0 + (size_t)(kt & 15) * 32768;
    gload16(base + 4096 + woff, sbl);
    gload16(base + 4096 + woff + 512, sbl + 512);
    if (WITH_Z) {
      const _Float16* sb = srcB00 + (size_t)kt * 32768;
      gload16(base + 8192 + woff, sb);
      gload16(base + 8192 + woff + 512, sb + 512);
    }
  };

  // prologue: stages 0 and 1 in flight; wait for stage 0 only.
  stage(0, 0);
  stage(1, 1);
  asm volatile("s_waitcnt vmcnt(%0)" :: "i"(D) : "memory");
  __builtin_amdgcn_s_barrier();

  int cur = 0;
  for (int kt = 0; kt < KT; kt++) {
    if (kt + 2 < KT) stage(cur == 0 ? 2 : cur - 1, kt + 2);  // (kt+2)%3

    const _Float16* base = lds[cur];
    h8 a[4], bl[4], b0[4];
#pragma unroll
    for (int m = 0; m < 4; m++) a[m] = *(const h8*)&base[(wr * 4 + m) * 512 + lane * 8];
    const bool doL = (!WITH_Z) || (kt < 16);
    if (doL) {
#pragma unroll
      for (int n = 0; n < 4; n++) bl[n] = *(const h8*)&base[4096 + (wc * 4 + n) * 512 + lane * 8];
    }
    if (WITH_Z) {
#pragma unroll
      for (int n = 0; n < 4; n++) b0[n] = *(const h8*)&base[8192 + (wc * 4 + n) * 512 + lane * 8];
    }
    asm volatile("s_waitcnt lgkmcnt(0)" ::: "memory");
    __builtin_amdgcn_sched_barrier(0);

    __builtin_amdgcn_s_setprio(1);
    if (doL) {
#pragma unroll
      for (int m = 0; m < 4; m++)
#pragma unroll
        for (int n = 0; n < 4; n++)
          accL[m][n] = __builtin_amdgcn_mfma_f32_16x16x32_f16(a[m], bl[n], accL[m][n], 0, 0, 0);
    }
    if (WITH_Z) {
#pragma unroll
      for (int m = 0; m < 4; m++)
#pragma unroll
        for (int n = 0; n < 4; n++)
          accZ[m][n] = __builtin_amdgcn_mfma_f32_16x16x32_f16(a[m], b0[n], accZ[m][n], 0, 0, 0);
    }
    __builtin_amdgcn_s_setprio(0);

    // counted wait: oldest outstanding beyond D belong to stage kt+1 -> done.
    if (kt + 2 < KT) asm volatile("s_waitcnt vmcnt(%0)" :: "i"(D) : "memory");
    else             asm volatile("s_waitcnt vmcnt(0)" ::: "memory");
    __builtin_amdgcn_sched_barrier(0);
    __builtin_amdgcn_s_barrier();

    cur = (cur == 2) ? 0 : cur + 1;
  }

  // epilogue: n-fragment index == gate g; lane lr picks output dim
  const int d = (bn * 2 + wc) * 16 + lr;
  const int row0 = bm * 128 + wr * 64;
  f4 bq = {0.f, 0.f, 0.f, 0.f};
  if (WITH_Z) bq = *(const f4*)&biasq[d * 4];
#pragma unroll
  for (int i = 0; i < 4; i++) {
#pragma unroll
    for (int r = 0; r < 4; r++) {
      const int row = row0 + i * 16 + lg * 4 + r;
      const size_t off = (size_t)row * Dd + d;
      float zi, zf, zo, zc;
      if (WITH_Z) {
        const float z0 = accZ[i][0][r] + bq.x;
        const float z1 = accZ[i][1][r] + bq.y;
        const float z2 = accZ[i][2][r] + bq.z;
        const float z3 = accZ[i][3][r] + bq.w;
        h4 oz;
        oz[0] = (_Float16)z0; oz[1] = (_Float16)z1;
        oz[2] = (_Float16)z2; oz[3] = (_Float16)z3;
        *(h4*)&zq[off * 4] = oz;
        zi = z0 + accL[i][0][r]; zf = z1 + accL[i][1][r];
        zo = z2 + accL[i][2][r]; zc = z3 + accL[i][3][r];
      } else {
        const h4 zb = *(const h4*)&zq[off * 4];
        zi = (float)zb[0] + accL[i][0][r]; zf = (float)zb[1] + accL[i][1][r];
        zo = (float)zb[2] + accL[i][2][r]; zc = (float)zb[3] + accL[i][3][r];
      }
      const float ig = fsigm(zi), fg = fsigm(zf), og = fsigm(zo), ci = ftanh(zc);
      const float cold = FIRST ? 0.f : cbuf[off];
      const float cn = fg * cold + ig * ci;
      const float hn = og * ftanh(cn);
      const float mk = mask[row];
      cbuf[off] = cn * mk;
      const float hm = hn * mk;
      reps[off] = hm;
      if (FIRST) h16[off] = (_Float16)hm;  // fp16 working h for iter-1 gather
      else       hbuf[off] = hm;           // final h output
    }
  }
}

// ---------------------------------------------------------------------------
extern "C" void kernel_launch(void* const* d_in, const int* in_sizes, int n_in,
                              void* d_out, int out_size, void* d_ws, size_t ws_size,
                              hipStream_t stream) {
  const float* node_reps = (const float*)d_in[0];
  const float* mask      = (const float*)d_in[1];
  const int*   in_idx    = (const int*)d_in[2];
  const int*   in_edges  = (const int*)d_in[3];
  const float* in_mask   = (const float*)d_in[4];
  const int*   out_idx   = (const int*)d_in[5];
  const int*   out_edges = (const int*)d_in[6];
  const float* out_mask  = (const float*)d_in[7];
  const float* edge_emb  = (const float*)d_in[8];
  const float* Wi  = (const float*)d_in[9];
  const float* Wo  = (const float*)d_in[10];
  const float* Ui  = (const float*)d_in[11];
  const float* Uo  = (const float*)d_in[12];
  const float* bi  = (const float*)d_in[13];
  const float* bo  = (const float*)d_in[14];
  const float* bui = (const float*)d_in[15];
  const float* buo = (const float*)d_in[16];

  float* out = (float*)d_out;
  const size_t MD = (size_t)MR * Dd;
  float* reps0 = out;
  float* reps1 = out + MD;
  float* hbuf  = out + 2 * MD;
  float* cbuf  = out + 3 * MD;

  _Float16* X    = (_Float16*)d_ws;                 // 16 MB
  _Float16* zq   = X + (size_t)MR * NC;             // 16 MB
  _Float16* W0f  = zq + (size_t)MR * NC;            // 640*1024 (1.25 MB)
  _Float16* Wlf  = W0f + 640 * 1024;                // 512*1024 (1 MB)
  _Float16* h16  = Wlf + 512 * 1024;                // 4 MB
  float*    biasq = (float*)(h16 + (size_t)MR * Dd);

  // 1. P-GEMM || fold || bias || agg0(f32 gathers + bins)
  mega_kernel<<<801, 256, 0, stream>>>(node_reps, edge_emb, in_idx, in_mask,
                                       out_idx, out_mask, in_edges, out_edges,
                                       Wi, Wo, Ui, Uo, bi, bo, bui, buo,
                                       X, W0f, Wlf, biasq);
  // 2. dual-acc GEMM: zbase (K=640) + iter-0 loop GEMM (K=512) + LSTM0
  fused_gemm<true, true><<<512, 256, 0, stream>>>(
      X, W0f, Wlf, biasq, zq, mask, reps0, nullptr, h16, cbuf);
  // 3. re-aggregate from fp16 h1
  agg1_kernel<<<512, 256, 0, stream>>>(h16, in_idx, in_mask, out_idx, out_mask, X);
  // 4. iter-1 GEMM (K=512) + LSTM1 -> final outputs
  fused_gemm<false, false><<<512, 256, 0, stream>>>(
      X, W0f, Wlf, biasq, zq, mask, reps1, hbuf, h16, cbuf);
}